// Round 10
// baseline (299.965 us; speedup 1.0000x reference)
//
#include <hip/hip_runtime.h>
#include <cstdint>

#define RR 8
#define D0 128
#define D1 64
#define D2 32
#define BINSH 8          // 256 nodes per bin
#define EPB 4096         // edges per bin-phase block (256 thr x 16)

typedef unsigned short u16;
typedef unsigned int u32;
typedef short short8 __attribute__((ext_vector_type(8)));
typedef float floatx4 __attribute__((ext_vector_type(4)));

static __device__ __forceinline__ float relu_f(float x) { return x > 0.f ? x : 0.f; }
static __device__ __forceinline__ float sigm_f(float x) { return 1.0f / (1.0f + __expf(-x)); }

static __device__ __forceinline__ u16 f2bf(float x) {
  unsigned int u = __float_as_uint(x);
  u += 0x7fffu + ((u >> 16) & 1u);   // RNE
  return (u16)(u >> 16);
}
static __device__ __forceinline__ float bf2f(u16 v) {
  return __uint_as_float(((unsigned int)v) << 16);
}

// ---- pack [W(r,k,o) | root(k,o)] -> BTf in MFMA FRAGMENT ORDER ----
static __device__ __forceinline__ void packBTf_body(
    const float* __restrict__ W, const float* __restrict__ root,
    u16* __restrict__ BTf, int K, int NKf, int FOUT, int NC, int YC, int i) {
  if (i >= NC * K) return;
  int j = i & 7, l = (i >> 3) & 63, rest = i >> 9;
  int ks = rest % NKf, ct = rest / NKf;
  int c = ct * 16 + (l & 15);
  int k = ks * 32 + (l >> 4) * 8 + j;
  float v;
  if (c < YC) { int r = c / FOUT, o = c - r * FOUT; v = W[((size_t)r * K + k) * FOUT + o]; }
  else        { int o = c - YC; v = root[(size_t)k * (NC - YC) + o]; }
  BTf[i] = f2bf(v);
}

// ---- merged: bin histogram (binA) + both weight packs ----
__global__ __launch_bounds__(256) void prep_k(
    const int* __restrict__ dstp, int E,
    const float* __restrict__ W1, const float* __restrict__ root1, u16* __restrict__ BT1,
    const float* __restrict__ W2, const float* __restrict__ root2, u16* __restrict__ BT2,
    int* __restrict__ histg, int NBIN, int NBLK, int nbBinA, int nbP1) {
  int b = blockIdx.x;
  if (b < nbBinA) {
    __shared__ int hist[512];
    int blk = b, t = threadIdx.x;
    for (int i = t; i < NBIN; i += 256) hist[i] = 0;
    __syncthreads();
    int base = blk * EPB + t;
#pragma unroll
    for (int j = 0; j < 16; ++j) {
      int e = base + j * 256;
      if (e < E) atomicAdd(&hist[dstp[e] >> BINSH], 1);
    }
    __syncthreads();
    for (int i = t; i < NBIN; i += 256) histg[(size_t)i * NBLK + blk] = hist[i];
  } else if (b < nbBinA + nbP1) {
    packBTf_body(W1, root1, BT1, D0, D0 / 32, D1, RR * D1 + D1, RR * D1,
                 (b - nbBinA) * 256 + threadIdx.x);
  } else {
    packBTf_body(W2, root2, BT2, D1, D1 / 32, D2, RR * D2 + D2, RR * D2,
                 (b - nbBinA - nbP1) * 256 + threadIdx.x);
  }
}

// ---- hist scan stage 1: per-block chunk sums (raw, unscanned) ----
__global__ __launch_bounds__(256) void hsum_k(
    const int* __restrict__ histg, int* __restrict__ hbsum, int hl) {
  __shared__ int sd[256];
  int b = blockIdx.x, t = threadIdx.x;
  int base = b * 1024 + t * 4;
  int s = 0;
#pragma unroll
  for (int j = 0; j < 4; ++j) { int i = base + j; if (i < hl) s += histg[i]; }
  sd[t] = s; __syncthreads();
  for (int st = 128; st > 0; st >>= 1) { if (t < st) sd[t] += sd[t + st]; __syncthreads(); }
  if (t == 0) hbsum[b] = sd[0];
}

// ---- hist scan stage 2+3 merged ----
__global__ void hscan3_k(const int* __restrict__ histg, const int* __restrict__ hbsum,
                         int* __restrict__ hscan, int hl, int nhb) {
  __shared__ int sd[256];
  __shared__ int sbase;
  int blk = blockIdx.x, t = threadIdx.x;
  int v = (t < nhb) ? hbsum[t] : 0;
  sd[t] = v; __syncthreads();
  for (int st = 1; st < 256; st <<= 1) {
    int x = (t >= st) ? sd[t - st] : 0;
    __syncthreads(); sd[t] += x; __syncthreads();
  }
  if (t == 0) sbase = (blk == 0) ? 0 : sd[blk - 1];
  __syncthreads();
  int base = sbase;
  int cb = blk * 1024 + t * 4;
  int vals[4]; int s = 0; int loc[4];
#pragma unroll
  for (int j = 0; j < 4; ++j) {
    int i = cb + j; int x = (i < hl) ? histg[i] : 0;
    vals[j] = x; loc[j] = s; s += x;
  }
  __syncthreads();
  sd[t] = s; __syncthreads();
  for (int st = 1; st < 256; st <<= 1) {
    int x = (t >= st) ? sd[t - st] : 0;
    __syncthreads(); sd[t] += x; __syncthreads();
  }
  int texcl = sd[t] - s;
#pragma unroll
  for (int j = 0; j < 4; ++j) {
    int i = cb + j;
    if (i < hl) {
      hscan[i] = base + texcl + loc[j];
      if (i == hl - 1) hscan[hl] = base + texcl + loc[j] + vals[j];
    }
  }
}

// ---- bf16 MFMA GEMM body (r4 structure — PROVEN: fragment-packed BT + LDS
// overlay Al->Yt + cooperative full-line uint4 epilogue stores. Direct
// per-lane stores regress (r2, r5): in-order vmcnt retirement makes
// interleaved stores serialize the next panel's loads). ----
template <int K, int NC, int YC, bool AF32>
static __device__ __forceinline__ void gemm_body(
    const void* __restrict__ Aptr, const u16* __restrict__ BTf,
    const float* __restrict__ bias, u16* __restrict__ Y,
    float* __restrict__ Xroot, int N, int rowBlk, u16* __restrict__ smem) {
  constexpr int KP = K + 8;
  constexpr int NK = K / 32;
  constexpr int NCT = NC / 16;
  constexpr int ROOTC = NC - YC;
  constexpr int CH = K / 8;
  constexpr int YTS = 72;                       // Yt row stride (bf16), 16B-aligned
  u16* const Al = smem;
  const int tid = threadIdx.x;

  if (AF32) {
    const float* A = (const float*)Aptr;
    for (int c = tid; c < 64 * CH; c += 256) {
      int row = c / CH, kc = c - row * CH;
      int gr = rowBlk * 64 + row; if (gr >= N) gr = N - 1;
      const float4* p = (const float4*)&A[(size_t)gr * K + kc * 8];
      float4 v0 = p[0], v1 = p[1];
      uint4 o;
      o.x = (u32)f2bf(v0.x) | ((u32)f2bf(v0.y) << 16);
      o.y = (u32)f2bf(v0.z) | ((u32)f2bf(v0.w) << 16);
      o.z = (u32)f2bf(v1.x) | ((u32)f2bf(v1.y) << 16);
      o.w = (u32)f2bf(v1.z) | ((u32)f2bf(v1.w) << 16);
      *(uint4*)&Al[row * KP + kc * 8] = o;
    }
  } else {
    const u16* A = (const u16*)Aptr;
    for (int c = tid; c < 64 * CH; c += 256) {
      int row = c / CH, kc = c - row * CH;
      int gr = rowBlk * 64 + row; if (gr >= N) gr = N - 1;
      *(uint4*)&Al[row * KP + kc * 8] = *(const uint4*)&A[(size_t)gr * K + kc * 8];
    }
  }
  __syncthreads();

  const int lane = tid & 63, wid = tid >> 6;
  const int l16 = lane & 15, quad = lane >> 4;
  const int wrow = (wid >> 1) * 32, wcol = (wid & 1) * 32;

  short8 af[2][NK];
#pragma unroll
  for (int ks = 0; ks < NK; ++ks) {
    int ko = ks * 32 + quad * 8;
    af[0][ks] = *(const short8*)&Al[(wrow +      l16) * KP + ko];
    af[1][ks] = *(const short8*)&Al[(wrow + 16 + l16) * KP + ko];
  }
  __syncthreads();   // Al is dead; smem is reused as Yt from here on

  int p = 0;
#pragma unroll
  for (int cb = 0; cb < NC; cb += 64, ++p) {
    int ct0 = (cb + wcol) >> 4; if (ct0 > NCT - 1) ct0 = NCT - 1;
    int ct1 = ct0 + 1;          if (ct1 > NCT - 1) ct1 = NCT - 1;

    short8 bf0[NK], bf1[NK];
#pragma unroll
    for (int ks = 0; ks < NK; ++ks) {
      bf0[ks] = *(const short8*)&BTf[((size_t)(ct0 * NK + ks) * 64 + lane) * 8];
      bf1[ks] = *(const short8*)&BTf[((size_t)(ct1 * NK + ks) * 64 + lane) * 8];
    }

    floatx4 acc[2][2] = {};
#pragma unroll
    for (int ks = 0; ks < NK; ++ks) {
      acc[0][0] = __builtin_amdgcn_mfma_f32_16x16x32_bf16(bf0[ks], af[0][ks], acc[0][0], 0, 0, 0);
      acc[0][1] = __builtin_amdgcn_mfma_f32_16x16x32_bf16(bf1[ks], af[0][ks], acc[0][1], 0, 0, 0);
      acc[1][0] = __builtin_amdgcn_mfma_f32_16x16x32_bf16(bf0[ks], af[1][ks], acc[1][0], 0, 0, 0);
      acc[1][1] = __builtin_amdgcn_mfma_f32_16x16x32_bf16(bf1[ks], af[1][ks], acc[1][1], 0, 0, 0);
    }

    if (cb + 64 <= YC) {          // compile-time: pure Y panel -> Yt staging
      u16* yt = smem + (p & 1) * (64 * YTS);
#pragma unroll
      for (int mi = 0; mi < 2; ++mi)
#pragma unroll
        for (int ni = 0; ni < 2; ++ni) {
          floatx4 v = acc[mi][ni];
          uint2 o;
          o.x = (u32)f2bf(v[0]) | ((u32)f2bf(v[1]) << 16);
          o.y = (u32)f2bf(v[2]) | ((u32)f2bf(v[3]) << 16);
          *(uint2*)&yt[(wrow + mi * 16 + l16) * YTS + wcol + ni * 16 + quad * 4] = o;
        }
    } else {                      // root panel (f32 + bias), direct store
#pragma unroll
      for (int mi = 0; mi < 2; ++mi) {
        int r = rowBlk * 64 + wrow + mi * 16 + l16;
        if (r >= N) continue;
#pragma unroll
        for (int ni = 0; ni < 2; ++ni) {
          int cbase = cb + wcol + ni * 16 + quad * 4;
          floatx4 v = acc[mi][ni];
          if (cbase >= YC && cbase < NC) {
            int o = cbase - YC;
            float4 w;
            w.x = v[0] + bias[o];     w.y = v[1] + bias[o + 1];
            w.z = v[2] + bias[o + 2]; w.w = v[3] + bias[o + 3];
            *(float4*)&Xroot[(size_t)r * ROOTC + o] = w;
          }
        }
      }
    }
    __syncthreads();
    if (cb + 64 <= YC) {
      const u16* yt = smem + (p & 1) * (64 * YTS);
#pragma unroll
      for (int u = tid; u < 512; u += 256) {
        int row = u >> 3, cg = u & 7;
        int gr = rowBlk * 64 + row;
        if (gr < N)
          *(uint4*)&Y[(size_t)gr * YC + cb + cg * 8] = *(const uint4*)&yt[row * YTS + cg * 8];
      }
    }
  }
}

template <int K, int NC, int YC, bool AF32>
__global__ __launch_bounds__(256) void gemm_k(
    const void* __restrict__ Aptr, const u16* __restrict__ BTf,
    const float* __restrict__ bias, u16* __restrict__ Y,
    float* __restrict__ Xroot, int N) {
  constexpr int AL_U16 = 64 * (K + 8);
  constexpr int YT_U16 = 2 * 64 * 72;
  constexpr int SM_U16 = AL_U16 > YT_U16 ? AL_U16 : YT_U16;
  __shared__ __align__(16) u16 smem[SM_U16];
  gemm_body<K, NC, YC, AF32>(Aptr, BTf, bias, Y, Xroot, N, blockIdx.x, smem);
}

// ---- bg1: binB pair-scatter (LDS cursors) + gemm layer-1 rowBlks [0,split).
// binB needs only hscan; gemm1 needs only BT1 — independent, so binB's ~25us
// hides under the first 60% of the layer-1 GEMM. ----
__global__ __launch_bounds__(256) void bg1_k(
    const void* __restrict__ emb, const u16* __restrict__ BT1, const float* __restrict__ b1,
    u16* __restrict__ Y, float* __restrict__ xr1, int N, int nbBinB,
    const int* __restrict__ src, const int* __restrict__ dstp, const int* __restrict__ et,
    const int* __restrict__ hscan, int2* __restrict__ pk, int NBIN, int NBLK, int E) {
  constexpr int AL_U16 = 64 * (D0 + 8);
  constexpr int YT_U16 = 2 * 64 * 72;
  constexpr int SM_U16 = AL_U16 > YT_U16 ? AL_U16 : YT_U16;
  __shared__ __align__(16) u16 smem[SM_U16];
  if ((int)blockIdx.x >= nbBinB) {
    gemm_body<D0, RR * D1 + D1, RR * D1, true>(emb, BT1, b1, Y, xr1, N,
                                               blockIdx.x - nbBinB, smem);
    return;
  }
  int* curB = (int*)smem;
  int blk = blockIdx.x, t = threadIdx.x;
  for (int i = t; i < NBIN; i += 256) curB[i] = hscan[(size_t)i * NBLK + blk];
  __syncthreads();
  int base = blk * EPB + t;
#pragma unroll
  for (int j = 0; j < 16; ++j) {
    int e = base + j * 256;
    if (e < E) {
      int d = dstp[e];
      int pos = atomicAdd(&curB[d >> BINSH], 1);
      pk[pos] = make_int2(src[e] * RR + et[e], d);
    }
  }
}

// ---- cg1: binC2 (count+invc+offs+place, all LDS) + gemm layer-1 rowBlks
// [split,end). binC2 needs all pk (kernel boundary after bg1 guarantees it)
// and hides under the remaining 40% of the layer-1 GEMM. ----
__global__ __launch_bounds__(256) void cg1_k(
    const void* __restrict__ emb, const u16* __restrict__ BT1, const float* __restrict__ b1,
    u16* __restrict__ Y, float* __restrict__ xr1, int N, int nbBinC, int rowBase,
    const int2* __restrict__ pk, const int* __restrict__ hscan,
    int* __restrict__ offs, float* __restrict__ invc, int* __restrict__ ssr,
    int NBIN, int NBLK, int E) {
  constexpr int AL_U16 = 64 * (D0 + 8);
  constexpr int YT_U16 = 2 * 64 * 72;
  constexpr int SM_U16 = AL_U16 > YT_U16 ? AL_U16 : YT_U16;
  __shared__ __align__(16) u16 smem[SM_U16];
  if ((int)blockIdx.x >= nbBinC) {
    gemm_body<D0, RR * D1 + D1, RR * D1, true>(emb, BT1, b1, Y, xr1, N,
                                               rowBase + (int)blockIdx.x - nbBinC, smem);
    return;
  }
  // ---- binC2 ---- (LDS overlay: cnt[2048] | tot[256] | sd[256] | curL[256])
  int* cnt  = (int*)smem;
  int* tot  = cnt + 2048;
  int* sd   = tot + 256;
  int* curL = sd + 256;
  int b = blockIdx.x, t = threadIdx.x;
  int beg = hscan[(size_t)b * NBLK];
  int end = hscan[(size_t)(b + 1) * NBLK];   // hscan[hl]==E covers last bin
  int node0 = b << BINSH;

  for (int i = t; i < 2048; i += 256) cnt[i] = 0;
  __syncthreads();
  for (int i = beg + t; i < end; i += 256) {
    int2 p = pk[i];
    atomicAdd(&cnt[((p.y - node0) << 3) + (p.x & 7)], 1);
  }
  __syncthreads();

  int d = node0 + t;
  int s = 0;
  float iv[RR];
#pragma unroll
  for (int r = 0; r < RR; ++r) {
    int c = cnt[(t << 3) + r];
    s += c;
    iv[r] = 1.0f / (float)(c > 1 ? c : 1);
  }
  if (d < N) {
#pragma unroll
    for (int r = 0; r < RR; ++r) invc[(size_t)d * RR + r] = iv[r];
  }
  sd[t] = s; __syncthreads();
  for (int st = 1; st < 256; st <<= 1) {
    int x = (t >= st) ? sd[t - st] : 0;
    __syncthreads(); sd[t] += x; __syncthreads();
  }
  int excl = sd[t] - s;
  tot[t] = excl;
  if (d < N) offs[d] = beg + excl;
  if (d == N - 1) offs[N] = beg + excl + s;
  curL[t] = 0;
  __syncthreads();

  for (int i = beg + t; i < end; i += 256) {
    int2 p = pk[i];
    int ln = p.y - node0;
    int r = atomicAdd(&curL[ln], 1);
    ssr[beg + tot[ln] + r] = p.x;
  }
}

// ---- layer-1 aggregation v4 (r8): 4 dsts/wave, 8 gathers in flight ----
__global__ __launch_bounds__(256) void agg1_k(
    const int* __restrict__ off, const int* __restrict__ ssr,
    const uint4* __restrict__ Yu, const float* __restrict__ invc,
    const float4* __restrict__ xroot, uint4* __restrict__ X1b, int N, int E) {
  int wid = threadIdx.x >> 6, lane = threadIdx.x & 63;
  int q = lane >> 4, l16 = lane & 15;
  int h = l16 >> 3, fi = l16 & 7;
  int d = blockIdx.x * 16 + wid * 4 + q;
  bool act = d < N;
  int beg = 0, end = 0;
  if (act) { beg = off[d]; end = off[d + 1]; }
  int deg = end - beg;
  int ei0 = beg + l16;      if (ei0 >= E) ei0 = E - 1;
  int ei1 = beg + 16 + l16; if (ei1 >= E) ei1 = E - 1;
  int e0 = ssr[ei0];
  int e1 = ssr[ei1];
  float a0 = 0.f, a1 = 0.f, a2 = 0.f, a3 = 0.f, a4 = 0.f, a5 = 0.f, a6 = 0.f, a7 = 0.f;
#define ACC1(s) { \
    float w = invc[(d << 3) + ((s) & 7)]; \
    uint4 y = Yu[(size_t)(s) * 8 + fi]; \
    a0 = fmaf(bf2f((u16)y.x), w, a0); a1 = fmaf(bf2f((u16)(y.x >> 16)), w, a1); \
    a2 = fmaf(bf2f((u16)y.y), w, a2); a3 = fmaf(bf2f((u16)(y.y >> 16)), w, a3); \
    a4 = fmaf(bf2f((u16)y.z), w, a4); a5 = fmaf(bf2f((u16)(y.z >> 16)), w, a5); \
    a6 = fmaf(bf2f((u16)y.w), w, a6); a7 = fmaf(bf2f((u16)(y.w >> 16)), w, a7); }
  {
    int j0 = 0 + h, j1 = 2 + h, j2 = 4 + h, j3 = 6 + h;
    int j4 = 8 + h, j5 = 10 + h, j6 = 12 + h, j7 = 14 + h;
    int s0 = __shfl(e0, q * 16 + j0), s1 = __shfl(e0, q * 16 + j1);
    int s2 = __shfl(e0, q * 16 + j2), s3 = __shfl(e0, q * 16 + j3);
    int s4 = __shfl(e0, q * 16 + j4), s5 = __shfl(e0, q * 16 + j5);
    int s6 = __shfl(e0, q * 16 + j6), s7 = __shfl(e0, q * 16 + j7);
    if (j0 < deg) ACC1(s0)
    if (j1 < deg) ACC1(s1)
    if (j2 < deg) ACC1(s2)
    if (j3 < deg) ACC1(s3)
    if (j4 < deg) ACC1(s4)
    if (j5 < deg) ACC1(s5)
    if (j6 < deg) ACC1(s6)
    if (j7 < deg) ACC1(s7)
    if (deg > 16) {
      int t0 = __shfl(e1, q * 16 + j0), t1 = __shfl(e1, q * 16 + j1);
      int t2 = __shfl(e1, q * 16 + j2), t3 = __shfl(e1, q * 16 + j3);
      int t4 = __shfl(e1, q * 16 + j4), t5 = __shfl(e1, q * 16 + j5);
      int t6 = __shfl(e1, q * 16 + j6), t7 = __shfl(e1, q * 16 + j7);
      if (16 + j0 < deg) ACC1(t0)
      if (16 + j1 < deg) ACC1(t1)
      if (16 + j2 < deg) ACC1(t2)
      if (16 + j3 < deg) ACC1(t3)
      if (16 + j4 < deg) ACC1(t4)
      if (16 + j5 < deg) ACC1(t5)
      if (16 + j6 < deg) ACC1(t6)
      if (16 + j7 < deg) ACC1(t7)
    }
  }
  if (deg > 32) {
    for (int i = beg + 32 + h; i < end; i += 2) {
      int sr = ssr[i];
      ACC1(sr)
    }
  }
#undef ACC1
  a0 += __shfl_xor(a0, 8); a1 += __shfl_xor(a1, 8);
  a2 += __shfl_xor(a2, 8); a3 += __shfl_xor(a3, 8);
  a4 += __shfl_xor(a4, 8); a5 += __shfl_xor(a5, 8);
  a6 += __shfl_xor(a6, 8); a7 += __shfl_xor(a7, 8);
  if (act && h == 0) {
    float4 xr0 = xroot[(size_t)d * 16 + fi * 2];
    float4 xr1 = xroot[(size_t)d * 16 + fi * 2 + 1];
    uint4 o;
    o.x = (u32)f2bf(relu_f(xr0.x + a0)) | ((u32)f2bf(relu_f(xr0.y + a1)) << 16);
    o.y = (u32)f2bf(relu_f(xr0.z + a2)) | ((u32)f2bf(relu_f(xr0.w + a3)) << 16);
    o.z = (u32)f2bf(relu_f(xr1.x + a4)) | ((u32)f2bf(relu_f(xr1.y + a5)) << 16);
    o.w = (u32)f2bf(relu_f(xr1.z + a6)) | ((u32)f2bf(relu_f(xr1.w + a7)) << 16);
    X1b[(size_t)d * 8 + fi] = o;
  }
}

// ---- layer-2 aggregation v4 (r8): 4 dsts/wave, 8 gathers in flight ----
__global__ __launch_bounds__(256) void agg2_k(
    const int* __restrict__ off, const int* __restrict__ ssr,
    const uint4* __restrict__ Yu, const float* __restrict__ invc,
    const float4* __restrict__ xroot, float4* __restrict__ out, int N, int E) {
  int wid = threadIdx.x >> 6, lane = threadIdx.x & 63;
  int q = lane >> 4, l16 = lane & 15;
  int h = l16 >> 2, fi = l16 & 3;
  int d = blockIdx.x * 16 + wid * 4 + q;
  bool act = d < N;
  int beg = 0, end = 0;
  if (act) { beg = off[d]; end = off[d + 1]; }
  int deg = end - beg;
  int ei0 = beg + l16;      if (ei0 >= E) ei0 = E - 1;
  int ei1 = beg + 16 + l16; if (ei1 >= E) ei1 = E - 1;
  int e0 = ssr[ei0];
  int e1 = ssr[ei1];
  float a0 = 0.f, a1 = 0.f, a2 = 0.f, a3 = 0.f, a4 = 0.f, a5 = 0.f, a6 = 0.f, a7 = 0.f;
#define ACC2(s) { \
    float w = invc[(d << 3) + ((s) & 7)]; \
    uint4 y = Yu[(size_t)(s) * 4 + fi]; \
    a0 = fmaf(bf2f((u16)y.x), w, a0); a1 = fmaf(bf2f((u16)(y.x >> 16)), w, a1); \
    a2 = fmaf(bf2f((u16)y.y), w, a2); a3 = fmaf(bf2f((u16)(y.y >> 16)), w, a3); \
    a4 = fmaf(bf2f((u16)y.z), w, a4); a5 = fmaf(bf2f((u16)(y.z >> 16)), w, a5); \
    a6 = fmaf(bf2f((u16)y.w), w, a6); a7 = fmaf(bf2f((u16)(y.w >> 16)), w, a7); }
  {
    int j0 = 0 + h, j1 = 4 + h, j2 = 8 + h, j3 = 12 + h;
    int s0 = __shfl(e0, q * 16 + j0), s1 = __shfl(e0, q * 16 + j1);
    int s2 = __shfl(e0, q * 16 + j2), s3 = __shfl(e0, q * 16 + j3);
    int s4 = __shfl(e1, q * 16 + j0), s5 = __shfl(e1, q * 16 + j1);
    int s6 = __shfl(e1, q * 16 + j2), s7 = __shfl(e1, q * 16 + j3);
    if (j0 < deg) ACC2(s0)
    if (j1 < deg) ACC2(s1)
    if (j2 < deg) ACC2(s2)
    if (j3 < deg) ACC2(s3)
    if (16 + j0 < deg) ACC2(s4)
    if (16 + j1 < deg) ACC2(s5)
    if (16 + j2 < deg) ACC2(s6)
    if (16 + j3 < deg) ACC2(s7)
  }
  if (deg > 32) {
    for (int i = beg + 32 + h; i < end; i += 4) {
      int sr = ssr[i];
      ACC2(sr)
    }
  }
#undef ACC2
  a0 += __shfl_xor(a0, 8); a1 += __shfl_xor(a1, 8);
  a2 += __shfl_xor(a2, 8); a3 += __shfl_xor(a3, 8);
  a4 += __shfl_xor(a4, 8); a5 += __shfl_xor(a5, 8);
  a6 += __shfl_xor(a6, 8); a7 += __shfl_xor(a7, 8);
  a0 += __shfl_xor(a0, 4); a1 += __shfl_xor(a1, 4);
  a2 += __shfl_xor(a2, 4); a3 += __shfl_xor(a3, 4);
  a4 += __shfl_xor(a4, 4); a5 += __shfl_xor(a5, 4);
  a6 += __shfl_xor(a6, 4); a7 += __shfl_xor(a7, 4);
  if (act && h == 0) {
    float4 xr0 = xroot[(size_t)d * 8 + fi * 2];
    float4 xr1 = xroot[(size_t)d * 8 + fi * 2 + 1];
    float4 o1, o2;
    o1.x = sigm_f(xr0.x + a0); o1.y = sigm_f(xr0.y + a1);
    o1.z = sigm_f(xr0.z + a2); o1.w = sigm_f(xr0.w + a3);
    o2.x = sigm_f(xr1.x + a4); o2.y = sigm_f(xr1.y + a5);
    o2.z = sigm_f(xr1.z + a6); o2.w = sigm_f(xr1.w + a7);
    out[(size_t)d * 8 + fi * 2]     = o1;
    out[(size_t)d * 8 + fi * 2 + 1] = o2;
  }
}

extern "C" void kernel_launch(void* const* d_in, const int* in_sizes, int n_in,
                              void* d_out, int out_size, void* d_ws, size_t ws_size,
                              hipStream_t stream) {
  const int*   edge_index = (const int*)d_in[0];
  const int*   et    = (const int*)d_in[1];
  const float* emb   = (const float*)d_in[2];
  const float* W1    = (const float*)d_in[3];
  const float* root1 = (const float*)d_in[4];
  const float* b1    = (const float*)d_in[5];
  const float* W2    = (const float*)d_in[6];
  const float* root2 = (const float*)d_in[7];
  const float* b2    = (const float*)d_in[8];
  float* out = (float*)d_out;

  const int E = in_sizes[1];
  const int N = in_sizes[2] / D0;
  const int* src  = edge_index;
  const int* dstp = edge_index + E;

  auto cdiv = [](size_t a, size_t b) { return (unsigned)((a + b - 1) / b); };

  const int NBLK = cdiv(E, EPB);          // bin-phase blocks
  const int NBIN = cdiv(N, 1 << BINSH);   // 256-node bins
  const int hl   = NBIN * NBLK;
  const int NHB  = cdiv(hl, 1024);

  char* ws = (char*)d_ws;
  size_t off_b = 0;
  auto alloc = [&](size_t bytes) { size_t o = off_b; off_b = (off_b + bytes + 255) & ~(size_t)255; return o; };
  float* invc   = (float*)(ws + alloc((size_t)N * RR * 4));
  int*   offs   = (int*)(ws + alloc((size_t)(N + 1) * 4));
  int*   hbsum  = (int*)(ws + alloc((size_t)256 * 4));
  int*   histg  = (int*)(ws + alloc((size_t)hl * 4));
  int*   hscan  = (int*)(ws + alloc((size_t)(hl + 1) * 4));
  int2*  pk     = (int2*)(ws + alloc((size_t)E * 8));
  int*   ssr    = (int*)(ws + alloc((size_t)E * 4));
  u16*   X1b    = (u16*)(ws + alloc((size_t)N * D1 * 2));
  float* xr1    = (float*)(ws + alloc((size_t)N * D1 * 4));
  float* xr2    = (float*)(ws + alloc((size_t)N * D2 * 4));
  u16*   BT1    = (u16*)(ws + alloc((size_t)(RR * D1 + D1) * D0 * 2));
  u16*   BT2    = (u16*)(ws + alloc((size_t)(RR * D2 + D2) * D1 * 2 + 8192)); // +pad
  u16*   Y      = (u16*)(ws + alloc((size_t)N * RR * D1 * 2));   // Y1; reused as Y2

  const int NC1 = RR * D1 + D1;
  const int NC2 = RR * D2 + D2;
  const int nbP1 = cdiv((size_t)NC1 * D0, 256);
  const int nbP2 = cdiv((size_t)NC2 * D1, 256);
  const int nbGemm1 = cdiv(N, 64);
  const int SPLITA = (nbGemm1 * 3) / 5;   // 60% of gemm1 covers binB; 40% covers binC2

  // 1. binA histogram + pack BT1f + pack BT2f
  prep_k<<<NBLK + nbP1 + nbP2, 256, 0, stream>>>(
      dstp, E, W1, root1, BT1, W2, root2, BT2, histg, NBIN, NBLK, NBLK, nbP1);
  // 2-3. 2-stage hist scan -> hscan
  hsum_k<<<NHB, 256, 0, stream>>>(histg, hbsum, hl);
  hscan3_k<<<NHB, 256, 0, stream>>>(histg, hbsum, hscan, hl, NHB);
  // 4. binB pair-scatter + gemm1 rowBlks [0, SPLITA)  (independent, overlapped)
  bg1_k<<<NBLK + SPLITA, 256, 0, stream>>>(emb, BT1, b1, Y, xr1, N, NBLK,
                                           src, dstp, et, hscan, pk, NBIN, NBLK, E);
  // 5. binC2 + gemm1 rowBlks [SPLITA, nbGemm1)  (kernel boundary orders pk)
  cg1_k<<<NBIN + (nbGemm1 - SPLITA), 256, 0, stream>>>(
      emb, BT1, b1, Y, xr1, N, NBIN, SPLITA,
      pk, hscan, offs, invc, ssr, NBIN, NBLK, E);
  // 6. aggregate layer-1 (4 dsts/wave, 8 gathers in flight)
  agg1_k<<<cdiv(N, 16), 256, 0, stream>>>(offs, ssr, (const uint4*)Y, invc,
                                          (const float4*)xr1, (uint4*)X1b, N, E);
  // 7. gemm layer-2
  gemm_k<D1, RR * D2 + D2, RR * D2, false><<<cdiv(N, 64), 256, 0, stream>>>(
      X1b, BT2, b2, Y, xr2, N);
  // 8. aggregate layer-2 (4 dsts/wave, 8 gathers in flight)
  agg2_k<<<cdiv(N, 16), 256, 0, stream>>>(offs, ssr, (const uint4*)Y, invc,
                                          (const float4*)xr2, (float4*)out, N, E);
}

// Round 11
// 291.365 us; speedup vs baseline: 1.0295x; 1.0295x over previous
//
#include <hip/hip_runtime.h>
#include <cstdint>

#define RR 8
#define D0 128
#define D1 64
#define D2 32
#define BINSH 8          // 256 nodes per bin
#define EPB 4096         // edges per bin-phase block (256 thr x 16)

typedef unsigned short u16;
typedef unsigned int u32;
typedef short short8 __attribute__((ext_vector_type(8)));
typedef float floatx4 __attribute__((ext_vector_type(4)));

static __device__ __forceinline__ float relu_f(float x) { return x > 0.f ? x : 0.f; }
static __device__ __forceinline__ float sigm_f(float x) { return 1.0f / (1.0f + __expf(-x)); }

static __device__ __forceinline__ u16 f2bf(float x) {
  unsigned int u = __float_as_uint(x);
  u += 0x7fffu + ((u >> 16) & 1u);   // RNE
  return (u16)(u >> 16);
}
static __device__ __forceinline__ float bf2f(u16 v) {
  return __uint_as_float(((unsigned int)v) << 16);
}

// ---- pack [W(r,k,o) | root(k,o)] -> BTf in MFMA FRAGMENT ORDER ----
static __device__ __forceinline__ void packBTf_body(
    const float* __restrict__ W, const float* __restrict__ root,
    u16* __restrict__ BTf, int K, int NKf, int FOUT, int NC, int YC, int i) {
  if (i >= NC * K) return;
  int j = i & 7, l = (i >> 3) & 63, rest = i >> 9;
  int ks = rest % NKf, ct = rest / NKf;
  int c = ct * 16 + (l & 15);
  int k = ks * 32 + (l >> 4) * 8 + j;
  float v;
  if (c < YC) { int r = c / FOUT, o = c - r * FOUT; v = W[((size_t)r * K + k) * FOUT + o]; }
  else        { int o = c - YC; v = root[(size_t)k * (NC - YC) + o]; }
  BTf[i] = f2bf(v);
}

// ---- merged: bin histogram (binA) + both weight packs ----
__global__ __launch_bounds__(256) void prep_k(
    const int* __restrict__ dstp, int E,
    const float* __restrict__ W1, const float* __restrict__ root1, u16* __restrict__ BT1,
    const float* __restrict__ W2, const float* __restrict__ root2, u16* __restrict__ BT2,
    int* __restrict__ histg, int NBIN, int NBLK, int nbBinA, int nbP1) {
  int b = blockIdx.x;
  if (b < nbBinA) {
    __shared__ int hist[512];
    int blk = b, t = threadIdx.x;
    for (int i = t; i < NBIN; i += 256) hist[i] = 0;
    __syncthreads();
    int base = blk * EPB + t;
#pragma unroll
    for (int j = 0; j < 16; ++j) {
      int e = base + j * 256;
      if (e < E) atomicAdd(&hist[dstp[e] >> BINSH], 1);
    }
    __syncthreads();
    for (int i = t; i < NBIN; i += 256) histg[(size_t)i * NBLK + blk] = hist[i];
  } else if (b < nbBinA + nbP1) {
    packBTf_body(W1, root1, BT1, D0, D0 / 32, D1, RR * D1 + D1, RR * D1,
                 (b - nbBinA) * 256 + threadIdx.x);
  } else {
    packBTf_body(W2, root2, BT2, D1, D1 / 32, D2, RR * D2 + D2, RR * D2,
                 (b - nbBinA - nbP1) * 256 + threadIdx.x);
  }
}

// ---- hist scan stage 1: per-block chunk sums (raw, unscanned) ----
__global__ __launch_bounds__(256) void hsum_k(
    const int* __restrict__ histg, int* __restrict__ hbsum, int hl) {
  __shared__ int sd[256];
  int b = blockIdx.x, t = threadIdx.x;
  int base = b * 1024 + t * 4;
  int s = 0;
#pragma unroll
  for (int j = 0; j < 4; ++j) { int i = base + j; if (i < hl) s += histg[i]; }
  sd[t] = s; __syncthreads();
  for (int st = 128; st > 0; st >>= 1) { if (t < st) sd[t] += sd[t + st]; __syncthreads(); }
  if (t == 0) hbsum[b] = sd[0];
}

// ---- hist scan stage 2+3 merged ----
__global__ void hscan3_k(const int* __restrict__ histg, const int* __restrict__ hbsum,
                         int* __restrict__ hscan, int hl, int nhb) {
  __shared__ int sd[256];
  __shared__ int sbase;
  int blk = blockIdx.x, t = threadIdx.x;
  int v = (t < nhb) ? hbsum[t] : 0;
  sd[t] = v; __syncthreads();
  for (int st = 1; st < 256; st <<= 1) {
    int x = (t >= st) ? sd[t - st] : 0;
    __syncthreads(); sd[t] += x; __syncthreads();
  }
  if (t == 0) sbase = (blk == 0) ? 0 : sd[blk - 1];
  __syncthreads();
  int base = sbase;
  int cb = blk * 1024 + t * 4;
  int vals[4]; int s = 0; int loc[4];
#pragma unroll
  for (int j = 0; j < 4; ++j) {
    int i = cb + j; int x = (i < hl) ? histg[i] : 0;
    vals[j] = x; loc[j] = s; s += x;
  }
  __syncthreads();
  sd[t] = s; __syncthreads();
  for (int st = 1; st < 256; st <<= 1) {
    int x = (t >= st) ? sd[t - st] : 0;
    __syncthreads(); sd[t] += x; __syncthreads();
  }
  int texcl = sd[t] - s;
#pragma unroll
  for (int j = 0; j < 4; ++j) {
    int i = cb + j;
    if (i < hl) {
      hscan[i] = base + texcl + loc[j];
      if (i == hl - 1) hscan[hl] = base + texcl + loc[j] + vals[j];
    }
  }
}

// ---- binB standalone: scatter PACKED edge words into bin regions.
// pk word = (sr << 8) | (dst & 255), sr = src*8+et (20 bits) — 4 B/edge
// instead of 8: halves the scatter-write and binC2-read traffic. The bin
// (dst >> 8) is implied by the region the word lands in. ----
__global__ __launch_bounds__(256) void binB_k(
    const int* __restrict__ src, const int* __restrict__ dstp, const int* __restrict__ et,
    const int* __restrict__ hscan, u32* __restrict__ pk, int NBIN, int NBLK, int E) {
  __shared__ int curB[512];
  int blk = blockIdx.x, t = threadIdx.x;
  for (int i = t; i < NBIN; i += 256) curB[i] = hscan[(size_t)i * NBLK + blk];
  __syncthreads();
  int base = blk * EPB + t;
#pragma unroll
  for (int j = 0; j < 16; ++j) {
    int e = base + j * 256;
    if (e < E) {
      int d = dstp[e];
      int pos = atomicAdd(&curB[d >> BINSH], 1);
      pk[pos] = ((u32)(src[e] * RR + et[e]) << 8) | (u32)(d & 255);
    }
  }
}

// ---- bf16 MFMA GEMM body (r4 structure — PROVEN: fragment-packed BT + LDS
// overlay Al->Yt + cooperative full-line uint4 epilogue stores. Direct
// per-lane stores regress (r2, r5): in-order vmcnt retirement makes
// interleaved stores serialize the next panel's loads). ----
template <int K, int NC, int YC, bool AF32>
static __device__ __forceinline__ void gemm_body(
    const void* __restrict__ Aptr, const u16* __restrict__ BTf,
    const float* __restrict__ bias, u16* __restrict__ Y,
    float* __restrict__ Xroot, int N, int rowBlk, u16* __restrict__ smem) {
  constexpr int KP = K + 8;
  constexpr int NK = K / 32;
  constexpr int NCT = NC / 16;
  constexpr int ROOTC = NC - YC;
  constexpr int CH = K / 8;
  constexpr int YTS = 72;                       // Yt row stride (bf16), 16B-aligned
  u16* const Al = smem;
  const int tid = threadIdx.x;

  if (AF32) {
    const float* A = (const float*)Aptr;
    for (int c = tid; c < 64 * CH; c += 256) {
      int row = c / CH, kc = c - row * CH;
      int gr = rowBlk * 64 + row; if (gr >= N) gr = N - 1;
      const float4* p = (const float4*)&A[(size_t)gr * K + kc * 8];
      float4 v0 = p[0], v1 = p[1];
      uint4 o;
      o.x = (u32)f2bf(v0.x) | ((u32)f2bf(v0.y) << 16);
      o.y = (u32)f2bf(v0.z) | ((u32)f2bf(v0.w) << 16);
      o.z = (u32)f2bf(v1.x) | ((u32)f2bf(v1.y) << 16);
      o.w = (u32)f2bf(v1.z) | ((u32)f2bf(v1.w) << 16);
      *(uint4*)&Al[row * KP + kc * 8] = o;
    }
  } else {
    const u16* A = (const u16*)Aptr;
    for (int c = tid; c < 64 * CH; c += 256) {
      int row = c / CH, kc = c - row * CH;
      int gr = rowBlk * 64 + row; if (gr >= N) gr = N - 1;
      *(uint4*)&Al[row * KP + kc * 8] = *(const uint4*)&A[(size_t)gr * K + kc * 8];
    }
  }
  __syncthreads();

  const int lane = tid & 63, wid = tid >> 6;
  const int l16 = lane & 15, quad = lane >> 4;
  const int wrow = (wid >> 1) * 32, wcol = (wid & 1) * 32;

  short8 af[2][NK];
#pragma unroll
  for (int ks = 0; ks < NK; ++ks) {
    int ko = ks * 32 + quad * 8;
    af[0][ks] = *(const short8*)&Al[(wrow +      l16) * KP + ko];
    af[1][ks] = *(const short8*)&Al[(wrow + 16 + l16) * KP + ko];
  }
  __syncthreads();   // Al is dead; smem is reused as Yt from here on

  int p = 0;
#pragma unroll
  for (int cb = 0; cb < NC; cb += 64, ++p) {
    int ct0 = (cb + wcol) >> 4; if (ct0 > NCT - 1) ct0 = NCT - 1;
    int ct1 = ct0 + 1;          if (ct1 > NCT - 1) ct1 = NCT - 1;

    short8 bf0[NK], bf1[NK];
#pragma unroll
    for (int ks = 0; ks < NK; ++ks) {
      bf0[ks] = *(const short8*)&BTf[((size_t)(ct0 * NK + ks) * 64 + lane) * 8];
      bf1[ks] = *(const short8*)&BTf[((size_t)(ct1 * NK + ks) * 64 + lane) * 8];
    }

    floatx4 acc[2][2] = {};
#pragma unroll
    for (int ks = 0; ks < NK; ++ks) {
      acc[0][0] = __builtin_amdgcn_mfma_f32_16x16x32_bf16(bf0[ks], af[0][ks], acc[0][0], 0, 0, 0);
      acc[0][1] = __builtin_amdgcn_mfma_f32_16x16x32_bf16(bf1[ks], af[0][ks], acc[0][1], 0, 0, 0);
      acc[1][0] = __builtin_amdgcn_mfma_f32_16x16x32_bf16(bf0[ks], af[1][ks], acc[1][0], 0, 0, 0);
      acc[1][1] = __builtin_amdgcn_mfma_f32_16x16x32_bf16(bf1[ks], af[1][ks], acc[1][1], 0, 0, 0);
    }

    if (cb + 64 <= YC) {          // compile-time: pure Y panel -> Yt staging
      u16* yt = smem + (p & 1) * (64 * YTS);
#pragma unroll
      for (int mi = 0; mi < 2; ++mi)
#pragma unroll
        for (int ni = 0; ni < 2; ++ni) {
          floatx4 v = acc[mi][ni];
          uint2 o;
          o.x = (u32)f2bf(v[0]) | ((u32)f2bf(v[1]) << 16);
          o.y = (u32)f2bf(v[2]) | ((u32)f2bf(v[3]) << 16);
          *(uint2*)&yt[(wrow + mi * 16 + l16) * YTS + wcol + ni * 16 + quad * 4] = o;
        }
    } else {                      // root panel (f32 + bias), direct store
#pragma unroll
      for (int mi = 0; mi < 2; ++mi) {
        int r = rowBlk * 64 + wrow + mi * 16 + l16;
        if (r >= N) continue;
#pragma unroll
        for (int ni = 0; ni < 2; ++ni) {
          int cbase = cb + wcol + ni * 16 + quad * 4;
          floatx4 v = acc[mi][ni];
          if (cbase >= YC && cbase < NC) {
            int o = cbase - YC;
            float4 w;
            w.x = v[0] + bias[o];     w.y = v[1] + bias[o + 1];
            w.z = v[2] + bias[o + 2]; w.w = v[3] + bias[o + 3];
            *(float4*)&Xroot[(size_t)r * ROOTC + o] = w;
          }
        }
      }
    }
    __syncthreads();
    if (cb + 64 <= YC) {
      const u16* yt = smem + (p & 1) * (64 * YTS);
#pragma unroll
      for (int u = tid; u < 512; u += 256) {
        int row = u >> 3, cg = u & 7;
        int gr = rowBlk * 64 + row;
        if (gr < N)
          *(uint4*)&Y[(size_t)gr * YC + cb + cg * 8] = *(const uint4*)&yt[row * YTS + cg * 8];
      }
    }
  }
}

template <int K, int NC, int YC, bool AF32>
__global__ __launch_bounds__(256) void gemm_k(
    const void* __restrict__ Aptr, const u16* __restrict__ BTf,
    const float* __restrict__ bias, u16* __restrict__ Y,
    float* __restrict__ Xroot, int N) {
  constexpr int AL_U16 = 64 * (K + 8);
  constexpr int YT_U16 = 2 * 64 * 72;
  constexpr int SM_U16 = AL_U16 > YT_U16 ? AL_U16 : YT_U16;
  __shared__ __align__(16) u16 smem[SM_U16];
  gemm_body<K, NC, YC, AF32>(Aptr, BTf, bias, Y, Xroot, N, blockIdx.x, smem);
}

// ---- merged: binC2 (count+invc+offs+place, all LDS; PACKED pk) + gemm layer-1. ----
__global__ __launch_bounds__(256) void pgB2_k(
    const void* __restrict__ emb, const u16* __restrict__ BT1, const float* __restrict__ b1,
    u16* __restrict__ Y, float* __restrict__ xr1, int N, int nbBinC,
    const u32* __restrict__ pk, const int* __restrict__ hscan,
    int* __restrict__ offs, float* __restrict__ invc, int* __restrict__ ssr,
    int NBIN, int NBLK, int E) {
  constexpr int AL_U16 = 64 * (D0 + 8);
  constexpr int YT_U16 = 2 * 64 * 72;
  constexpr int SM_U16 = AL_U16 > YT_U16 ? AL_U16 : YT_U16;
  __shared__ __align__(16) u16 smem[SM_U16];
  if ((int)blockIdx.x >= nbBinC) {
    gemm_body<D0, RR * D1 + D1, RR * D1, true>(emb, BT1, b1, Y, xr1, N,
                                               blockIdx.x - nbBinC, smem);
    return;
  }
  // ---- binC2 ---- (LDS overlay: cnt[2048] | tot[256] | sd[256] | curL[256])
  int* cnt  = (int*)smem;
  int* tot  = cnt + 2048;
  int* sd   = tot + 256;
  int* curL = sd + 256;
  int b = blockIdx.x, t = threadIdx.x;
  int beg = hscan[(size_t)b * NBLK];
  int end = hscan[(size_t)(b + 1) * NBLK];   // hscan[hl]==E covers last bin
  int node0 = b << BINSH;

  for (int i = t; i < 2048; i += 256) cnt[i] = 0;
  __syncthreads();
  for (int i = beg + t; i < end; i += 256) {
    u32 p = pk[i];
    atomicAdd(&cnt[((p & 255u) << 3) + ((p >> 8) & 7u)], 1);
  }
  __syncthreads();

  int d = node0 + t;
  int s = 0;
  float iv[RR];
#pragma unroll
  for (int r = 0; r < RR; ++r) {
    int c = cnt[(t << 3) + r];
    s += c;
    iv[r] = 1.0f / (float)(c > 1 ? c : 1);
  }
  if (d < N) {
#pragma unroll
    for (int r = 0; r < RR; ++r) invc[(size_t)d * RR + r] = iv[r];
  }
  sd[t] = s; __syncthreads();
  for (int st = 1; st < 256; st <<= 1) {
    int x = (t >= st) ? sd[t - st] : 0;
    __syncthreads(); sd[t] += x; __syncthreads();
  }
  int excl = sd[t] - s;
  tot[t] = excl;
  if (d < N) offs[d] = beg + excl;
  if (d == N - 1) offs[N] = beg + excl + s;
  curL[t] = 0;
  __syncthreads();

  for (int i = beg + t; i < end; i += 256) {
    u32 p = pk[i];
    int ln = (int)(p & 255u);
    int r = atomicAdd(&curL[ln], 1);
    ssr[beg + tot[ln] + r] = (int)(p >> 8);
  }
}

// ---- layer-1 aggregation v4 (r8): 4 dsts/wave, 8 gathers in flight ----
__global__ __launch_bounds__(256) void agg1_k(
    const int* __restrict__ off, const int* __restrict__ ssr,
    const uint4* __restrict__ Yu, const float* __restrict__ invc,
    const float4* __restrict__ xroot, uint4* __restrict__ X1b, int N, int E) {
  int wid = threadIdx.x >> 6, lane = threadIdx.x & 63;
  int q = lane >> 4, l16 = lane & 15;
  int h = l16 >> 3, fi = l16 & 7;
  int d = blockIdx.x * 16 + wid * 4 + q;
  bool act = d < N;
  int beg = 0, end = 0;
  if (act) { beg = off[d]; end = off[d + 1]; }
  int deg = end - beg;
  int ei0 = beg + l16;      if (ei0 >= E) ei0 = E - 1;
  int ei1 = beg + 16 + l16; if (ei1 >= E) ei1 = E - 1;
  int e0 = ssr[ei0];
  int e1 = ssr[ei1];
  float a0 = 0.f, a1 = 0.f, a2 = 0.f, a3 = 0.f, a4 = 0.f, a5 = 0.f, a6 = 0.f, a7 = 0.f;
#define ACC1(s) { \
    float w = invc[(d << 3) + ((s) & 7)]; \
    uint4 y = Yu[(size_t)(s) * 8 + fi]; \
    a0 = fmaf(bf2f((u16)y.x), w, a0); a1 = fmaf(bf2f((u16)(y.x >> 16)), w, a1); \
    a2 = fmaf(bf2f((u16)y.y), w, a2); a3 = fmaf(bf2f((u16)(y.y >> 16)), w, a3); \
    a4 = fmaf(bf2f((u16)y.z), w, a4); a5 = fmaf(bf2f((u16)(y.z >> 16)), w, a5); \
    a6 = fmaf(bf2f((u16)y.w), w, a6); a7 = fmaf(bf2f((u16)(y.w >> 16)), w, a7); }
  {
    int j0 = 0 + h, j1 = 2 + h, j2 = 4 + h, j3 = 6 + h;
    int j4 = 8 + h, j5 = 10 + h, j6 = 12 + h, j7 = 14 + h;
    int s0 = __shfl(e0, q * 16 + j0), s1 = __shfl(e0, q * 16 + j1);
    int s2 = __shfl(e0, q * 16 + j2), s3 = __shfl(e0, q * 16 + j3);
    int s4 = __shfl(e0, q * 16 + j4), s5 = __shfl(e0, q * 16 + j5);
    int s6 = __shfl(e0, q * 16 + j6), s7 = __shfl(e0, q * 16 + j7);
    if (j0 < deg) ACC1(s0)
    if (j1 < deg) ACC1(s1)
    if (j2 < deg) ACC1(s2)
    if (j3 < deg) ACC1(s3)
    if (j4 < deg) ACC1(s4)
    if (j5 < deg) ACC1(s5)
    if (j6 < deg) ACC1(s6)
    if (j7 < deg) ACC1(s7)
    if (deg > 16) {
      int t0 = __shfl(e1, q * 16 + j0), t1 = __shfl(e1, q * 16 + j1);
      int t2 = __shfl(e1, q * 16 + j2), t3 = __shfl(e1, q * 16 + j3);
      int t4 = __shfl(e1, q * 16 + j4), t5 = __shfl(e1, q * 16 + j5);
      int t6 = __shfl(e1, q * 16 + j6), t7 = __shfl(e1, q * 16 + j7);
      if (16 + j0 < deg) ACC1(t0)
      if (16 + j1 < deg) ACC1(t1)
      if (16 + j2 < deg) ACC1(t2)
      if (16 + j3 < deg) ACC1(t3)
      if (16 + j4 < deg) ACC1(t4)
      if (16 + j5 < deg) ACC1(t5)
      if (16 + j6 < deg) ACC1(t6)
      if (16 + j7 < deg) ACC1(t7)
    }
  }
  if (deg > 32) {
    for (int i = beg + 32 + h; i < end; i += 2) {
      int sr = ssr[i];
      ACC1(sr)
    }
  }
#undef ACC1
  a0 += __shfl_xor(a0, 8); a1 += __shfl_xor(a1, 8);
  a2 += __shfl_xor(a2, 8); a3 += __shfl_xor(a3, 8);
  a4 += __shfl_xor(a4, 8); a5 += __shfl_xor(a5, 8);
  a6 += __shfl_xor(a6, 8); a7 += __shfl_xor(a7, 8);
  if (act && h == 0) {
    float4 xr0 = xroot[(size_t)d * 16 + fi * 2];
    float4 xr1 = xroot[(size_t)d * 16 + fi * 2 + 1];
    uint4 o;
    o.x = (u32)f2bf(relu_f(xr0.x + a0)) | ((u32)f2bf(relu_f(xr0.y + a1)) << 16);
    o.y = (u32)f2bf(relu_f(xr0.z + a2)) | ((u32)f2bf(relu_f(xr0.w + a3)) << 16);
    o.z = (u32)f2bf(relu_f(xr1.x + a4)) | ((u32)f2bf(relu_f(xr1.y + a5)) << 16);
    o.w = (u32)f2bf(relu_f(xr1.z + a6)) | ((u32)f2bf(relu_f(xr1.w + a7)) << 16);
    X1b[(size_t)d * 8 + fi] = o;
  }
}

// ---- layer-2 aggregation v4 (r8): 4 dsts/wave, 8 gathers in flight ----
__global__ __launch_bounds__(256) void agg2_k(
    const int* __restrict__ off, const int* __restrict__ ssr,
    const uint4* __restrict__ Yu, const float* __restrict__ invc,
    const float4* __restrict__ xroot, float4* __restrict__ out, int N, int E) {
  int wid = threadIdx.x >> 6, lane = threadIdx.x & 63;
  int q = lane >> 4, l16 = lane & 15;
  int h = l16 >> 2, fi = l16 & 3;
  int d = blockIdx.x * 16 + wid * 4 + q;
  bool act = d < N;
  int beg = 0, end = 0;
  if (act) { beg = off[d]; end = off[d + 1]; }
  int deg = end - beg;
  int ei0 = beg + l16;      if (ei0 >= E) ei0 = E - 1;
  int ei1 = beg + 16 + l16; if (ei1 >= E) ei1 = E - 1;
  int e0 = ssr[ei0];
  int e1 = ssr[ei1];
  float a0 = 0.f, a1 = 0.f, a2 = 0.f, a3 = 0.f, a4 = 0.f, a5 = 0.f, a6 = 0.f, a7 = 0.f;
#define ACC2(s) { \
    float w = invc[(d << 3) + ((s) & 7)]; \
    uint4 y = Yu[(size_t)(s) * 4 + fi]; \
    a0 = fmaf(bf2f((u16)y.x), w, a0); a1 = fmaf(bf2f((u16)(y.x >> 16)), w, a1); \
    a2 = fmaf(bf2f((u16)y.y), w, a2); a3 = fmaf(bf2f((u16)(y.y >> 16)), w, a3); \
    a4 = fmaf(bf2f((u16)y.z), w, a4); a5 = fmaf(bf2f((u16)(y.z >> 16)), w, a5); \
    a6 = fmaf(bf2f((u16)y.w), w, a6); a7 = fmaf(bf2f((u16)(y.w >> 16)), w, a7); }
  {
    int j0 = 0 + h, j1 = 4 + h, j2 = 8 + h, j3 = 12 + h;
    int s0 = __shfl(e0, q * 16 + j0), s1 = __shfl(e0, q * 16 + j1);
    int s2 = __shfl(e0, q * 16 + j2), s3 = __shfl(e0, q * 16 + j3);
    int s4 = __shfl(e1, q * 16 + j0), s5 = __shfl(e1, q * 16 + j1);
    int s6 = __shfl(e1, q * 16 + j2), s7 = __shfl(e1, q * 16 + j3);
    if (j0 < deg) ACC2(s0)
    if (j1 < deg) ACC2(s1)
    if (j2 < deg) ACC2(s2)
    if (j3 < deg) ACC2(s3)
    if (16 + j0 < deg) ACC2(s4)
    if (16 + j1 < deg) ACC2(s5)
    if (16 + j2 < deg) ACC2(s6)
    if (16 + j3 < deg) ACC2(s7)
  }
  if (deg > 32) {
    for (int i = beg + 32 + h; i < end; i += 4) {
      int sr = ssr[i];
      ACC2(sr)
    }
  }
#undef ACC2
  a0 += __shfl_xor(a0, 8); a1 += __shfl_xor(a1, 8);
  a2 += __shfl_xor(a2, 8); a3 += __shfl_xor(a3, 8);
  a4 += __shfl_xor(a4, 8); a5 += __shfl_xor(a5, 8);
  a6 += __shfl_xor(a6, 8); a7 += __shfl_xor(a7, 8);
  a0 += __shfl_xor(a0, 4); a1 += __shfl_xor(a1, 4);
  a2 += __shfl_xor(a2, 4); a3 += __shfl_xor(a3, 4);
  a4 += __shfl_xor(a4, 4); a5 += __shfl_xor(a5, 4);
  a6 += __shfl_xor(a6, 4); a7 += __shfl_xor(a7, 4);
  if (act && h == 0) {
    float4 xr0 = xroot[(size_t)d * 8 + fi * 2];
    float4 xr1 = xroot[(size_t)d * 8 + fi * 2 + 1];
    float4 o1, o2;
    o1.x = sigm_f(xr0.x + a0); o1.y = sigm_f(xr0.y + a1);
    o1.z = sigm_f(xr0.z + a2); o1.w = sigm_f(xr0.w + a3);
    o2.x = sigm_f(xr1.x + a4); o2.y = sigm_f(xr1.y + a5);
    o2.z = sigm_f(xr1.z + a6); o2.w = sigm_f(xr1.w + a7);
    out[(size_t)d * 8 + fi * 2]     = o1;
    out[(size_t)d * 8 + fi * 2 + 1] = o2;
  }
}

extern "C" void kernel_launch(void* const* d_in, const int* in_sizes, int n_in,
                              void* d_out, int out_size, void* d_ws, size_t ws_size,
                              hipStream_t stream) {
  const int*   edge_index = (const int*)d_in[0];
  const int*   et    = (const int*)d_in[1];
  const float* emb   = (const float*)d_in[2];
  const float* W1    = (const float*)d_in[3];
  const float* root1 = (const float*)d_in[4];
  const float* b1    = (const float*)d_in[5];
  const float* W2    = (const float*)d_in[6];
  const float* root2 = (const float*)d_in[7];
  const float* b2    = (const float*)d_in[8];
  float* out = (float*)d_out;

  const int E = in_sizes[1];
  const int N = in_sizes[2] / D0;
  const int* src  = edge_index;
  const int* dstp = edge_index + E;

  auto cdiv = [](size_t a, size_t b) { return (unsigned)((a + b - 1) / b); };

  const int NBLK = cdiv(E, EPB);          // bin-phase blocks
  const int NBIN = cdiv(N, 1 << BINSH);   // 256-node bins
  const int hl   = NBIN * NBLK;
  const int NHB  = cdiv(hl, 1024);

  char* ws = (char*)d_ws;
  size_t off_b = 0;
  auto alloc = [&](size_t bytes) { size_t o = off_b; off_b = (off_b + bytes + 255) & ~(size_t)255; return o; };
  float* invc   = (float*)(ws + alloc((size_t)N * RR * 4));
  int*   offs   = (int*)(ws + alloc((size_t)(N + 1) * 4));
  int*   hbsum  = (int*)(ws + alloc((size_t)256 * 4));
  int*   histg  = (int*)(ws + alloc((size_t)hl * 4));
  int*   hscan  = (int*)(ws + alloc((size_t)(hl + 1) * 4));
  u32*   pk     = (u32*)(ws + alloc((size_t)E * 4));
  int*   ssr    = (int*)(ws + alloc((size_t)E * 4));
  u16*   X1b    = (u16*)(ws + alloc((size_t)N * D1 * 2));
  float* xr1    = (float*)(ws + alloc((size_t)N * D1 * 4));
  float* xr2    = (float*)(ws + alloc((size_t)N * D2 * 4));
  u16*   BT1    = (u16*)(ws + alloc((size_t)(RR * D1 + D1) * D0 * 2));
  u16*   BT2    = (u16*)(ws + alloc((size_t)(RR * D2 + D2) * D1 * 2 + 8192)); // +pad
  u16*   Y      = (u16*)(ws + alloc((size_t)N * RR * D1 * 2));   // Y1; reused as Y2

  const int NC1 = RR * D1 + D1;
  const int NC2 = RR * D2 + D2;
  const int nbP1 = cdiv((size_t)NC1 * D0, 256);
  const int nbP2 = cdiv((size_t)NC2 * D1, 256);
  const int nbGemm1 = cdiv(N, 64);

  // 1. binA histogram + pack BT1f + pack BT2f
  prep_k<<<NBLK + nbP1 + nbP2, 256, 0, stream>>>(
      dstp, E, W1, root1, BT1, W2, root2, BT2, histg, NBIN, NBLK, NBLK, nbP1);
  // 2-3. 2-stage hist scan -> hscan
  hsum_k<<<NHB, 256, 0, stream>>>(histg, hbsum, hl);
  hscan3_k<<<NHB, 256, 0, stream>>>(histg, hbsum, hscan, hl, NHB);
  // 4. binB pair-scatter (LDS cursors; PACKED 4B words)
  binB_k<<<NBLK, 256, 0, stream>>>(src, dstp, et, hscan, pk, NBIN, NBLK, E);
  // 5. binC2 (count+invc+offs+place) + gemm layer-1 (merged; binC2 hides under gemm)
  pgB2_k<<<NBIN + nbGemm1, 256, 0, stream>>>(emb, BT1, b1, Y, xr1, N, NBIN,
                                             pk, hscan, offs, invc, ssr, NBIN, NBLK, E);
  // 6. aggregate layer-1 (4 dsts/wave, 8 gathers in flight)
  agg1_k<<<cdiv(N, 16), 256, 0, stream>>>(offs, ssr, (const uint4*)Y, invc,
                                          (const float4*)xr1, (uint4*)X1b, N, E);
  // 7. gemm layer-2
  gemm_k<D1, RR * D2 + D2, RR * D2, false><<<cdiv(N, 64), 256, 0, stream>>>(
      X1b, BT2, b2, Y, xr2, N);
  // 8. aggregate layer-2 (4 dsts/wave, 8 gathers in flight)
  agg2_k<<<cdiv(N, 16), 256, 0, stream>>>(offs, ssr, (const uint4*)Y, invc,
                                          (const float4*)xr2, (float4*)out, N, E);
}